// Round 5
// baseline (28.193 us; speedup 1.0000x reference)
//
#include <hip/hip_runtime.h>
#include <math.h>

#define SEQ 8192
#define HID 4096

// ---------------------------------------------------------------------------
// Kernel 1: energies[r] = dot(encoder_outputs[r, :], hidden[:])
// One 64-lane wave per row, 4 rows per 256-thread block, 2048 blocks =
// exactly 8 blocks/CU (uniform, no tail). 16x fully-coalesced float4 loads
// per lane (1 KiB/instruction/wave); hidden hits L1 after first block.
// BW-bound at ~5.7-5.8 TB/s effective (92% of 6.3 TB/s copy ceiling);
// LDS-staging A/B (R4) was neutral -> direct loads kept.
// ---------------------------------------------------------------------------
__global__ __launch_bounds__(256) void matvec_kernel(
    const float* __restrict__ hidden,     // [HID]
    const float* __restrict__ eo,         // [SEQ, HID]
    float* __restrict__ energies)         // [SEQ]
{
    const int gwave = (blockIdx.x * blockDim.x + threadIdx.x) >> 6;  // row id
    const int lane  = threadIdx.x & 63;

    const float4* __restrict__ row = (const float4*)(eo + (size_t)gwave * HID);
    const float4* __restrict__ hv  = (const float4*)hidden;

    float acc = 0.0f;
#pragma unroll
    for (int k = 0; k < 16; ++k) {
        float4 a = row[k * 64 + lane];
        float4 b = hv [k * 64 + lane];    // L1-resident after first touch
        acc = fmaf(a.x, b.x, acc);
        acc = fmaf(a.y, b.y, acc);
        acc = fmaf(a.z, b.z, acc);
        acc = fmaf(a.w, b.w, acc);
    }

#pragma unroll
    for (int off = 32; off > 0; off >>= 1)
        acc += __shfl_xor(acc, off, 64);
    if (lane == 0) energies[gwave] = acc;
}

// ---------------------------------------------------------------------------
// Kernel 2: out = softmax(energies). Single block, 1024 threads (16 waves of
// TLP to hide the scattered cross-XCD latency of the energies reads),
// 8 values/thread in registers across the three passes.
// ---------------------------------------------------------------------------
__global__ __launch_bounds__(1024) void softmax_kernel(
    const float* __restrict__ energies,   // [SEQ]
    float* __restrict__ out)              // [SEQ]
{
    __shared__ float redm[16];
    __shared__ float reds[16];
    const int tid  = threadIdx.x;
    const int wid  = tid >> 6;            // 0..15
    const int lane = tid & 63;

    const float4* __restrict__ e4 = (const float4*)energies;
    float4* __restrict__ o4 = (float4*)out;

    float4 v[2];
    float m = -INFINITY;
#pragma unroll
    for (int i = 0; i < 2; ++i) {
        v[i] = e4[i * 1024 + tid];
        m = fmaxf(m, fmaxf(fmaxf(v[i].x, v[i].y), fmaxf(v[i].z, v[i].w)));
    }
#pragma unroll
    for (int off = 32; off > 0; off >>= 1)
        m = fmaxf(m, __shfl_xor(m, off, 64));
    if (lane == 0) redm[wid] = m;
    __syncthreads();
    float gmax = redm[0];
#pragma unroll
    for (int i = 1; i < 16; ++i) gmax = fmaxf(gmax, redm[i]);

    float s = 0.0f;
#pragma unroll
    for (int i = 0; i < 2; ++i) {
        v[i].x = __expf(v[i].x - gmax);
        v[i].y = __expf(v[i].y - gmax);
        v[i].z = __expf(v[i].z - gmax);
        v[i].w = __expf(v[i].w - gmax);
        s += (v[i].x + v[i].y) + (v[i].z + v[i].w);
    }
#pragma unroll
    for (int off = 32; off > 0; off >>= 1)
        s += __shfl_xor(s, off, 64);
    if (lane == 0) reds[wid] = s;
    __syncthreads();
    float total = reds[0];
#pragma unroll
    for (int i = 1; i < 16; ++i) total += reds[i];
    const float inv = 1.0f / total;

#pragma unroll
    for (int i = 0; i < 2; ++i) {
        float4 w = v[i];
        w.x *= inv; w.y *= inv; w.z *= inv; w.w *= inv;
        o4[i * 1024 + tid] = w;
    }
}

extern "C" void kernel_launch(void* const* d_in, const int* in_sizes, int n_in,
                              void* d_out, int out_size, void* d_ws, size_t ws_size,
                              hipStream_t stream) {
    const float* hidden = (const float*)d_in[0];   // [1, 4096] fp32
    const float* eo     = (const float*)d_in[1];   // [8192, 4096] fp32
    float* out          = (float*)d_out;           // [1, 1, 8192] fp32
    float* energies     = (float*)d_ws;            // 8192 floats scratch

    matvec_kernel<<<SEQ / 4, 256, 0, stream>>>(hidden, eo, energies);
    softmax_kernel<<<1, 1024, 0, stream>>>(energies, out);
}